// Round 1
// baseline (414.312 us; speedup 1.0000x reference)
//
#include <hip/hip_runtime.h>

// Problem constants (fixed by setup_inputs):
//   x: (16, 3, 1024, 1024) f32; control_points: (1, 2, 35, 35) f32
//   out = concat(transformed (16,3,1024,1024), deformation_field (2,1024,1024))
#define HW      1024
#define PLANE   (HW * HW)
#define NPLANES 48          // 16 * 3
#define CP      35
#define CPN     (CP * CP)

__global__ __launch_bounds__(256) void bspline_fused_kernel(
    const float* __restrict__ x,
    const float* __restrict__ cp,   // (2, 35, 35)
    float* __restrict__ out)
{
    const int j = blockIdx.x * blockDim.x + threadIdx.x;   // col
    const int i = blockIdx.y;                              // row
    const int pix = i * HW + j;

    // normalized grid coords (linspace(-1,1,1024))
    const float gx = (float)j * (2.0f / 1023.0f) - 1.0f;
    const float gy = (float)i * (2.0f / 1023.0f) - 1.0f;

    // ---- deformation field: bilinear sample of control points ----
    // cp_grid in "pixel" coords, then grid_sample re-normalizes (verbatim ref math)
    const float cpxc = gx * 17.0f + 17.0f;     // (cpx-1)/2 = 17
    const float cpyc = gy * 17.0f + 17.0f;
    float ix = (cpxc + 1.0f) * 0.5f * 34.0f;   // (W-1) = 34
    float iy = (cpyc + 1.0f) * 0.5f * 34.0f;
    ix = fminf(fmaxf(ix, 0.0f), 34.0f);
    iy = fminf(fmaxf(iy, 0.0f), 34.0f);
    const float ix0f = floorf(ix), iy0f = floorf(iy);
    const float wx = ix - ix0f,    wy = iy - iy0f;
    const int ix0 = (int)ix0f, iy0 = (int)iy0f;
    const int ix1 = min(ix0 + 1, 34), iy1 = min(iy0 + 1, 34);

    const int o00c = iy0 * CP + ix0, o01c = iy0 * CP + ix1;
    const int o10c = iy1 * CP + ix0, o11c = iy1 * CP + ix1;

    float df[2];
    #pragma unroll
    for (int c = 0; c < 2; ++c) {
        const float* cpc = cp + c * CPN;
        const float v00 = cpc[o00c], v01 = cpc[o01c];
        const float v10 = cpc[o10c], v11 = cpc[o11c];
        const float top = v00 * (1.0f - wx) + v01 * wx;
        const float bot = v10 * (1.0f - wx) + v11 * wx;
        df[c] = top * (1.0f - wy) + bot * wy;
    }

    // deformation_field output lives after the 48 transformed planes
    out[NPLANES * PLANE + 0 * PLANE + pix] = df[0];
    out[NPLANES * PLANE + 1 * PLANE + pix] = df[1];

    // ---- image sampling coords (note df channel swap per reference) ----
    const float sxn = gx + df[1];
    const float syn = gy + df[0];
    float fx = (sxn + 1.0f) * 0.5f * 1023.0f;
    float fy = (syn + 1.0f) * 0.5f * 1023.0f;
    fx = fminf(fmaxf(fx, 0.0f), 1023.0f);
    fy = fminf(fmaxf(fy, 0.0f), 1023.0f);
    const float fx0f = floorf(fx), fy0f = floorf(fy);
    const float ux = fx - fx0f,    uy = fy - fy0f;
    const int X0 = (int)fx0f, Y0 = (int)fy0f;
    const int X1 = min(X0 + 1, 1023), Y1 = min(Y0 + 1, 1023);

    const int o00 = Y0 * HW + X0, o01 = Y0 * HW + X1;
    const int o10 = Y1 * HW + X0, o11 = Y1 * HW + X1;
    const float omux = 1.0f - ux, omuy = 1.0f - uy;

    const float* __restrict__ xp = x;
    float* __restrict__ op = out + pix;
    #pragma unroll 4
    for (int p = 0; p < NPLANES; ++p) {
        const float v00 = xp[o00], v01 = xp[o01];
        const float v10 = xp[o10], v11 = xp[o11];
        const float top = v00 * omux + v01 * ux;
        const float bot = v10 * omux + v11 * ux;
        const float r   = top * omuy + bot * uy;
        __builtin_nontemporal_store(r, op);
        xp += PLANE;
        op += PLANE;
    }
}

extern "C" void kernel_launch(void* const* d_in, const int* in_sizes, int n_in,
                              void* d_out, int out_size, void* d_ws, size_t ws_size,
                              hipStream_t stream) {
    const float* x  = (const float*)d_in[0];
    const float* cp = (const float*)d_in[1];
    float* out = (float*)d_out;

    dim3 block(256, 1, 1);
    dim3 grid(HW / 256, HW, 1);
    bspline_fused_kernel<<<grid, block, 0, stream>>>(x, cp, out);
}

// Round 2
// 398.156 us; speedup vs baseline: 1.0406x; 1.0406x over previous
//
#include <hip/hip_runtime.h>

// Problem constants (fixed by setup_inputs):
//   x: (16, 3, 1024, 1024) f32; control_points: (1, 2, 35, 35) f32
//   out = concat(transformed (16,3,1024,1024), deformation_field (2,1024,1024))
#define HW      1024
#define PLANE   (HW * HW)
#define NPLANES 48          // 16 * 3
#define CP      35
#define CPN     (CP * CP)
#define PPT     8           // planes per thread
#define ZCHUNKS (NPLANES / PPT)   // 6

__global__ __launch_bounds__(256) void bspline_fused_kernel(
    const float* __restrict__ x,
    const float* __restrict__ cp,   // (2, 35, 35)
    float* __restrict__ out)
{
    const int j = blockIdx.x * blockDim.x + threadIdx.x;   // col
    const int i = blockIdx.y;                              // row
    const int pix = i * HW + j;

    // normalized grid coords (linspace(-1,1,1024))
    const float gx = (float)j * (2.0f / 1023.0f) - 1.0f;
    const float gy = (float)i * (2.0f / 1023.0f) - 1.0f;

    // ---- deformation field: bilinear sample of control points ----
    // cp_grid in "pixel" coords, then grid_sample re-normalizes (verbatim ref math)
    const float cpxc = gx * 17.0f + 17.0f;     // (cpx-1)/2 = 17
    const float cpyc = gy * 17.0f + 17.0f;
    float ix = (cpxc + 1.0f) * 0.5f * 34.0f;   // (W-1) = 34
    float iy = (cpyc + 1.0f) * 0.5f * 34.0f;
    ix = fminf(fmaxf(ix, 0.0f), 34.0f);
    iy = fminf(fmaxf(iy, 0.0f), 34.0f);
    const float ix0f = floorf(ix), iy0f = floorf(iy);
    const float wx = ix - ix0f,    wy = iy - iy0f;
    const int ix0 = (int)ix0f, iy0 = (int)iy0f;
    const int ix1 = min(ix0 + 1, 34), iy1 = min(iy0 + 1, 34);

    const int o00c = iy0 * CP + ix0, o01c = iy0 * CP + ix1;
    const int o10c = iy1 * CP + ix0, o11c = iy1 * CP + ix1;

    float df[2];
    #pragma unroll
    for (int c = 0; c < 2; ++c) {
        const float* cpc = cp + c * CPN;
        const float v00 = cpc[o00c], v01 = cpc[o01c];
        const float v10 = cpc[o10c], v11 = cpc[o11c];
        const float top = v00 * (1.0f - wx) + v01 * wx;
        const float bot = v10 * (1.0f - wx) + v11 * wx;
        df[c] = top * (1.0f - wy) + bot * wy;
    }

    // deformation_field output lives after the 48 transformed planes;
    // only the z==0 slice writes it (deterministic, identical every call)
    if (blockIdx.z == 0) {
        out[NPLANES * PLANE + 0 * PLANE + pix] = df[0];
        out[NPLANES * PLANE + 1 * PLANE + pix] = df[1];
    }

    // ---- image sampling coords (note df channel swap per reference) ----
    const float sxn = gx + df[1];
    const float syn = gy + df[0];
    float fx = (sxn + 1.0f) * 0.5f * 1023.0f;
    float fy = (syn + 1.0f) * 0.5f * 1023.0f;
    fx = fminf(fmaxf(fx, 0.0f), 1023.0f);
    fy = fminf(fmaxf(fy, 0.0f), 1023.0f);
    const float fx0f = floorf(fx), fy0f = floorf(fy);
    const float ux = fx - fx0f,    uy = fy - fy0f;
    const int X0 = (int)fx0f, Y0 = (int)fy0f;
    const int X1 = min(X0 + 1, 1023), Y1 = min(Y0 + 1, 1023);

    const int o00 = Y0 * HW + X0, o01 = Y0 * HW + X1;
    const int o10 = Y1 * HW + X0, o11 = Y1 * HW + X1;
    const float omux = 1.0f - ux, omuy = 1.0f - uy;

    // ---- 8 planes per thread, fully unrolled: 32 independent gathers ----
    const int p0 = blockIdx.z * PPT;
    const float* __restrict__ xp = x + (size_t)p0 * PLANE;
    float* __restrict__ op = out + (size_t)p0 * PLANE + pix;

    float v00[PPT], v01[PPT], v10[PPT], v11[PPT];
    #pragma unroll
    for (int p = 0; p < PPT; ++p) {
        const float* b = xp + (size_t)p * PLANE;
        v00[p] = b[o00];
        v01[p] = b[o01];
        v10[p] = b[o10];
        v11[p] = b[o11];
    }
    #pragma unroll
    for (int p = 0; p < PPT; ++p) {
        const float top = v00[p] * omux + v01[p] * ux;
        const float bot = v10[p] * omux + v11[p] * ux;
        const float r   = top * omuy + bot * uy;
        __builtin_nontemporal_store(r, op + (size_t)p * PLANE);
    }
}

extern "C" void kernel_launch(void* const* d_in, const int* in_sizes, int n_in,
                              void* d_out, int out_size, void* d_ws, size_t ws_size,
                              hipStream_t stream) {
    const float* x  = (const float*)d_in[0];
    const float* cp = (const float*)d_in[1];
    float* out = (float*)d_out;

    dim3 block(256, 1, 1);
    dim3 grid(HW / 256, HW, ZCHUNKS);
    bspline_fused_kernel<<<grid, block, 0, stream>>>(x, cp, out);
}